// Round 10
// baseline (202.829 us; speedup 1.0000x reference)
//
#include <hip/hip_runtime.h>

// Problem constants
#define BB    128
#define CC    272
#define CPAD  288     // K padded to 9*32 (rows 272..287 zeroed in LDS)
#define TT    512
#define DD1   320
#define NT    64      // t-tile per block
#define MT    160     // d-tile per block (D1 split in 2)
#define LDC   66      // Xs row stride, bf16 elems (132 B): conflict-free gathers (R9: 0 conflicts)

typedef float  f32x4  __attribute__((ext_vector_type(4)));
typedef __bf16 bf16x4 __attribute__((ext_vector_type(4)));
typedef __bf16 bf16x8 __attribute__((ext_vector_type(8)));

// lgkm-only barrier: orders LDS ops without draining vmcnt (global prefetch
// issued before it stays in flight).
#define BAR() asm volatile("s_waitcnt lgkmcnt(0)\ns_barrier" ::: "memory")

// ---- prepass: W f32 -> bf16 into workspace
__global__ __launch_bounds__(256)
void w_cvt(const float* __restrict__ W, __bf16* __restrict__ Wb) {
    const int i = blockIdx.x * 256 + threadIdx.x;      // 87040 threads
    const float4* src = (const float4*)W;
    const float4 a = src[2 * i];
    const float4 b = src[2 * i + 1];
    bf16x8 h = {(__bf16)a.x, (__bf16)a.y, (__bf16)a.z, (__bf16)a.w,
                (__bf16)b.x, (__bf16)b.y, (__bf16)b.z, (__bf16)b.w};
    *(bf16x8*)(Wb + 8 * i) = h;
}

// ---- shared helpers (identical to R9's verified code paths)
__device__ __forceinline__ void stage_X(const float* __restrict__ Xb,
                                        __bf16* __restrict__ Xs, int tid) {
    const int xr = tid >> 4;              // 0..15
    const int xt = (tid & 15) * 4;        // 256B/row per instruction, coalesced
#pragma unroll
    for (int pb = 0; pb < 3; ++pb) {
        float4 v[6];
#pragma unroll
        for (int q = 0; q < 6; ++q) {
            const int c = xr + 16 * (pb * 6 + q);
            v[q] = make_float4(0.f, 0.f, 0.f, 0.f);
            if (c < CC) v[q] = *(const float4*)(Xb + (size_t)c * TT + xt);
        }
#pragma unroll
        for (int q = 0; q < 6; ++q) {
            const int c = xr + 16 * (pb * 6 + q);
            bf16x4 h = {(__bf16)v[q].x, (__bf16)v[q].y,
                        (__bf16)v[q].z, (__bf16)v[q].w};
            *(bf16x4*)&Xs[c * LDC + xt] = h;
        }
    }
}

__device__ __forceinline__ void epilogue(float* __restrict__ out, const f32x4 acc[5][2],
                                         int b, int d0, int T0,
                                         int wm, int wn, int quad, int l16) {
#pragma unroll
    for (int mt = 0; mt < 5; ++mt) {
        const int d = d0 + wm * 80 + mt * 16 + quad * 4;
#pragma unroll
        for (int nt = 0; nt < 2; ++nt) {
            float* ob = out + ((size_t)b * DD1 + d) * TT + T0 + wn * 32 + nt * 16 + l16;
#pragma unroll
            for (int r = 0; r < 4; ++r)
                ob[(size_t)r * TT] = acc[mt][nt][r];
        }
    }
}

// ================= DIAGNOSTIC PROBE =================
// R9 kernel with the W af-load stream removed (af := b0). Writes garbage to
// out (fully overwritten by the final kernel). Measures the time of
// {X staging + LDS b-gathers + MFMA issue + epilogue stores} alone.
__global__ __launch_bounds__(256, 4)
void subj_probe(const float* __restrict__ X, float* __restrict__ out) {
    const int b  = blockIdx.x;
    const int T0 = blockIdx.y * NT;
    const int d0 = blockIdx.z * MT;

    __shared__ __align__(16) __bf16 Xs[CPAD * LDC];

    const int tid  = threadIdx.x;
    const int lane = tid & 63;
    const int wv   = tid >> 6;
    const int wm   = wv & 1;
    const int wn   = wv >> 1;
    const int quad = lane >> 4;
    const int l16  = lane & 15;

    stage_X(X + (size_t)b * CC * TT + T0, Xs, tid);
    __syncthreads();

    f32x4 acc[5][2];
#pragma unroll
    for (int mt = 0; mt < 5; ++mt) {
        acc[mt][0] = (f32x4){0.f, 0.f, 0.f, 0.f};
        acc[mt][1] = (f32x4){0.f, 0.f, 0.f, 0.f};
    }

    const int tc0 = wn * 32 + l16;
    const int tc1 = tc0 + 16;
#pragma unroll
    for (int kc = 0; kc < 9; ++kc) {
        bf16x8 b0, b1;
#pragma unroll
        for (int j = 0; j < 8; ++j) {
            const int crow = (kc * 32 + quad * 8 + j) * LDC;
            b0[j] = Xs[crow + tc0];
            b1[j] = Xs[crow + tc1];
        }
#pragma unroll
        for (int mt = 0; mt < 5; ++mt) {
            acc[mt][0] = __builtin_amdgcn_mfma_f32_16x16x32_bf16(b0, b0, acc[mt][0], 0, 0, 0);
            acc[mt][1] = __builtin_amdgcn_mfma_f32_16x16x32_bf16(b0, b1, acc[mt][1], 0, 0, 0);
        }
    }
    epilogue(out, acc, b, d0, T0, wm, wn, quad, l16);
}

// ================= DEEP-PREFETCH MAIN =================
// R9 structure + explicit software pipeline:
//   af (W fragments, global, ~200-300cy L2): DEPTH-2 — af[kc+2] issued
//     immediately after af[kc] is consumed by its MFMA pair.
//   b  (X fragments, LDS, ~120cy): DEPTH-1 — gathered at top of body kc for kc+1.
// (256,3) gives the allocator 170 VGPRs so it cannot pick R9's 52-reg
// load->use serial schedule (acc40 + af40 + b16 + addr ~ 120-150 expected).
template <bool WB16>
__global__ __launch_bounds__(256, 3)
void subj_conv_deep(const float*  __restrict__ X,
                    const int*    __restrict__ sidx,
                    const float*  __restrict__ W,
                    const __bf16* __restrict__ Wbf,
                    float*        __restrict__ out) {
    const int b  = blockIdx.x;
    const int T0 = blockIdx.y * NT;
    const int d0 = blockIdx.z * MT;
    const int s  = sidx[b];

    __shared__ __align__(16) __bf16 Xs[CPAD * LDC];

    const int tid  = threadIdx.x;
    const int lane = tid & 63;
    const int wv   = tid >> 6;
    const int wm   = wv & 1;
    const int wn   = wv >> 1;
    const int quad = lane >> 4;
    const int l16  = lane & 15;

    stage_X(X + (size_t)b * CC * TT + T0, Xs, tid);

    // per-lane W fragment base: d-row = d0+wm*80+mt*16+l16, k-octet = quad*8
    const size_t wrow = ((size_t)s * DD1 + d0 + wm * 80 + l16) * CC + quad * 8;
    const __bf16* Wp16 = Wbf + (WB16 ? wrow : 0);
    const float*  Wp32 = W   + (WB16 ? 0 : wrow);

    auto load_af = [&](int mt, int kc) -> bf16x8 {   // caller guarantees liveness
        const int off = mt * 16 * CC + kc * 32;
        if constexpr (WB16) {
            return *(const bf16x8*)(Wp16 + off);
        } else {
            const float4 u0 = *(const float4*)(Wp32 + off);
            const float4 u1 = *(const float4*)(Wp32 + off + 4);
            return bf16x8{(__bf16)u0.x, (__bf16)u0.y, (__bf16)u0.z, (__bf16)u0.w,
                          (__bf16)u1.x, (__bf16)u1.y, (__bf16)u1.z, (__bf16)u1.w};
        }
    };

    bf16x8 af[2][5];          // two named sets; all indices compile-time (full unroll)
    bf16x8 bf[2][2];

    // prologue: af for kc=0,1 issued BEFORE the barrier (lgkm-only -> stay in flight)
#pragma unroll
    for (int mt = 0; mt < 5; ++mt) af[0][mt] = load_af(mt, 0);
#pragma unroll
    for (int mt = 0; mt < 5; ++mt) af[1][mt] = load_af(mt, 1);
    BAR();

    const int tc0 = wn * 32 + l16;
    const int tc1 = tc0 + 16;
    // b frags for kc=0
#pragma unroll
    for (int j = 0; j < 8; ++j) {
        const int crow = (quad * 8 + j) * LDC;
        bf[0][0][j] = Xs[crow + tc0];
        bf[0][1][j] = Xs[crow + tc1];
    }

    f32x4 acc[5][2];
#pragma unroll
    for (int mt = 0; mt < 5; ++mt) {
        acc[mt][0] = (f32x4){0.f, 0.f, 0.f, 0.f};
        acc[mt][1] = (f32x4){0.f, 0.f, 0.f, 0.f};
    }

#pragma unroll
    for (int kc = 0; kc < 9; ++kc) {
        const int cur = kc & 1;
        const int nx  = cur ^ 1;
        // depth-1 LDS prefetch: b frags for kc+1 (consumed next body)
        if (kc + 1 < 9) {
#pragma unroll
            for (int j = 0; j < 8; ++j) {
                const int crow = ((kc + 1) * 32 + quad * 8 + j) * LDC;
                bf[nx][0][j] = Xs[crow + tc0];
                bf[nx][1][j] = Xs[crow + tc1];
            }
        }
#pragma unroll
        for (int mt = 0; mt < 5; ++mt) {
            // consume af[cur][mt] ...
            acc[mt][0] = __builtin_amdgcn_mfma_f32_16x16x32_bf16(af[cur][mt], bf[cur][0],
                                                                 acc[mt][0], 0, 0, 0);
            acc[mt][1] = __builtin_amdgcn_mfma_f32_16x16x32_bf16(af[cur][mt], bf[cur][1],
                                                                 acc[mt][1], 0, 0, 0);
            // ... then immediately re-fill the slot with kc+2 (depth-2, ~2 bodies of slack)
            if (kc + 2 < 8) {
                af[cur][mt] = load_af(mt, kc + 2);
            } else if (kc + 2 == 8) {
                bf16x8 a = {(__bf16)0.f, (__bf16)0.f, (__bf16)0.f, (__bf16)0.f,
                            (__bf16)0.f, (__bf16)0.f, (__bf16)0.f, (__bf16)0.f};
                if (quad < 2) a = load_af(mt, 8);   // k 256..287: only quads 0,1 in-bounds
                af[cur][mt] = a;
            }
        }
    }

    epilogue(out, acc, b, d0, T0, wm, wn, quad, l16);
}

extern "C" void kernel_launch(void* const* d_in, const int* in_sizes, int n_in,
                              void* d_out, int out_size, void* d_ws, size_t ws_size,
                              hipStream_t stream) {
    const float* X    = (const float*)d_in[0];   // [B, C, T]
    const int*   sidx = (const int*)  d_in[1];   // [B]
    const float* W    = (const float*)d_in[2];   // [S, D1, C]
    float*       out  = (float*)d_out;           // [B, D1, T]

    dim3 grid(BB, TT / NT, 2);   // 128 x 8 x 2 = 2048 blocks
    dim3 block(256);

    const size_t need = (size_t)8 * DD1 * CC * sizeof(__bf16);   // 1,392,640 B
    if (d_ws && ws_size >= need) {
        __bf16* Wb = (__bf16*)d_ws;
        w_cvt<<<dim3(340), dim3(256), 0, stream>>>(W, Wb);
        subj_probe<<<grid, block, 0, stream>>>(X, out);                       // diagnostic (garbage out)
        subj_conv_deep<true><<<grid, block, 0, stream>>>(X, sidx, W, Wb, out); // correct result, runs last
    } else {
        subj_probe<<<grid, block, 0, stream>>>(X, out);
        subj_conv_deep<false><<<grid, block, 0, stream>>>(X, sidx, W, nullptr, out);
    }
}

// Round 11
// 164.224 us; speedup vs baseline: 1.2351x; 1.2351x over previous
//
#include <hip/hip_runtime.h>

// Problem constants
#define BB    128
#define CC    272
#define CPAD  288     // K padded to 9*32 (rows 272..287 zeroed in LDS)
#define TT    512
#define DD1   320
#define NT    64      // t-tile per block
#define LDC   66      // Xs row stride, bf16 elems (132 B): conflict-free gathers (R9/R10: 0 conflicts)

typedef float  f32x4  __attribute__((ext_vector_type(4)));
typedef __bf16 bf16x4 __attribute__((ext_vector_type(4)));
typedef __bf16 bf16x8 __attribute__((ext_vector_type(8)));

// lgkm-only barrier: orders LDS ops without draining vmcnt (global af-prefetch
// issued before it stays in flight).
#define BAR() asm volatile("s_waitcnt lgkmcnt(0)\ns_barrier" ::: "memory")

// ---- prepass: W f32 -> bf16 into workspace
__global__ __launch_bounds__(256)
void w_cvt(const float* __restrict__ W, __bf16* __restrict__ Wb) {
    const int i = blockIdx.x * 256 + threadIdx.x;      // 87040 threads
    const float4* src = (const float4*)W;
    const float4 a = src[2 * i];
    const float4 b = src[2 * i + 1];
    bf16x8 h = {(__bf16)a.x, (__bf16)a.y, (__bf16)a.z, (__bf16)a.w,
                (__bf16)b.x, (__bf16)b.y, (__bf16)b.z, (__bf16)b.w};
    *(bf16x8*)(Wb + 8 * i) = h;
}

// out[b,d,t] = sum_c W[s_b,d,c] * X[b,c,t]
// Grid (B, T/NT) = 1024 blocks, 512 thr / 8 waves as 4(m) x 2(n).
// MT=320: one block covers ALL d for its (b,T0) — X tile staged ONCE
// (was twice across the d0-split), halving staging work and the L2 X re-read.
// Barrier-free K-loop (R9) + deep prefetch (R10, ~47us): af (W frags,
// global, L2-hot) at depth 2; b (X frags, LDS) at depth 1; per-wave shape
// (5 mt x 2 nt, 90 MFMA) identical to the verified R10 kernel.
template <bool WB16>
__global__ __launch_bounds__(512, 4)
void subj_conv_deep(const float*  __restrict__ X,
                    const int*    __restrict__ sidx,
                    const float*  __restrict__ W,
                    const __bf16* __restrict__ Wbf,
                    float*        __restrict__ out) {
    const int b  = blockIdx.x;
    const int T0 = blockIdx.y * NT;
    const int s  = sidx[b];

    __shared__ __align__(16) __bf16 Xs[CPAD * LDC];   // 38,016 B -> 2 blocks/CU at VGPR<=128

    const int tid  = threadIdx.x;
    const int lane = tid & 63;
    const int wv   = tid >> 6;        // 0..7
    const int wm   = wv & 3;          // m-quarter (80 rows each, 4*80 = 320)
    const int wn   = wv >> 2;         // n-half (32 t)
    const int quad = lane >> 4;
    const int l16  = lane & 15;

    // ---- stage full-K X tile once: f32 coalesced loads -> bf16 [c][t] rows.
    // 288 rows x 64 t / 512 thr = 9 passes; batched 3 to keep loads in flight.
    {
        const float* Xb = X + (size_t)b * CC * TT + T0;
        const int xr = tid >> 4;              // 0..31
        const int xt = (tid & 15) * 4;
#pragma unroll
        for (int pb = 0; pb < 3; ++pb) {
            float4 v[3];
#pragma unroll
            for (int q = 0; q < 3; ++q) {
                const int c = xr + 32 * (pb * 3 + q);
                v[q] = make_float4(0.f, 0.f, 0.f, 0.f);
                if (c < CC) v[q] = *(const float4*)(Xb + (size_t)c * TT + xt);
            }
#pragma unroll
            for (int q = 0; q < 3; ++q) {
                const int c = xr + 32 * (pb * 3 + q);
                bf16x4 h = {(__bf16)v[q].x, (__bf16)v[q].y,
                            (__bf16)v[q].z, (__bf16)v[q].w};
                *(bf16x4*)&Xs[c * LDC + xt] = h;
            }
        }
    }

    // per-lane W fragment base: d-row = wm*80 + mt*16 + l16, k-octet = quad*8
    const size_t wrow = ((size_t)s * DD1 + wm * 80 + l16) * CC + quad * 8;
    const __bf16* Wp16 = Wbf + (WB16 ? wrow : 0);
    const float*  Wp32 = W   + (WB16 ? 0 : wrow);

    auto load_af = [&](int mt, int kc) -> bf16x8 {   // caller guarantees liveness
        const int off = mt * 16 * CC + kc * 32;
        if constexpr (WB16) {
            return *(const bf16x8*)(Wp16 + off);
        } else {
            const float4 u0 = *(const float4*)(Wp32 + off);
            const float4 u1 = *(const float4*)(Wp32 + off + 4);
            return bf16x8{(__bf16)u0.x, (__bf16)u0.y, (__bf16)u0.z, (__bf16)u0.w,
                          (__bf16)u1.x, (__bf16)u1.y, (__bf16)u1.z, (__bf16)u1.w};
        }
    };

    bf16x8 af[2][5];          // two named sets; all indices compile-time (full unroll)
    bf16x8 bf[2][2];

    // prologue: af for kc=0,1 issued BEFORE the barrier (lgkm-only -> stay in flight)
#pragma unroll
    for (int mt = 0; mt < 5; ++mt) af[0][mt] = load_af(mt, 0);
#pragma unroll
    for (int mt = 0; mt < 5; ++mt) af[1][mt] = load_af(mt, 1);
    BAR();

    const int tc0 = wn * 32 + l16;
    const int tc1 = tc0 + 16;
    // b frags for kc=0
#pragma unroll
    for (int j = 0; j < 8; ++j) {
        const int crow = (quad * 8 + j) * LDC;
        bf[0][0][j] = Xs[crow + tc0];
        bf[0][1][j] = Xs[crow + tc1];
    }

    f32x4 acc[5][2];
#pragma unroll
    for (int mt = 0; mt < 5; ++mt) {
        acc[mt][0] = (f32x4){0.f, 0.f, 0.f, 0.f};
        acc[mt][1] = (f32x4){0.f, 0.f, 0.f, 0.f};
    }

#pragma unroll
    for (int kc = 0; kc < 9; ++kc) {
        const int cur = kc & 1;
        const int nx  = cur ^ 1;
        // depth-1 LDS prefetch: b frags for kc+1 (consumed next body)
        if (kc + 1 < 9) {
#pragma unroll
            for (int j = 0; j < 8; ++j) {
                const int crow = ((kc + 1) * 32 + quad * 8 + j) * LDC;
                bf[nx][0][j] = Xs[crow + tc0];
                bf[nx][1][j] = Xs[crow + tc1];
            }
        }
#pragma unroll
        for (int mt = 0; mt < 5; ++mt) {
            // consume af[cur][mt] ...
            acc[mt][0] = __builtin_amdgcn_mfma_f32_16x16x32_bf16(af[cur][mt], bf[cur][0],
                                                                 acc[mt][0], 0, 0, 0);
            acc[mt][1] = __builtin_amdgcn_mfma_f32_16x16x32_bf16(af[cur][mt], bf[cur][1],
                                                                 acc[mt][1], 0, 0, 0);
            // ... then immediately re-fill the slot with kc+2 (depth-2, ~2 bodies of slack)
            if (kc + 2 < 8) {
                af[cur][mt] = load_af(mt, kc + 2);
            } else if (kc + 2 == 8) {
                bf16x8 a = {(__bf16)0.f, (__bf16)0.f, (__bf16)0.f, (__bf16)0.f,
                            (__bf16)0.f, (__bf16)0.f, (__bf16)0.f, (__bf16)0.f};
                if (quad < 2) a = load_af(mt, 8);   // k 256..287: only quads 0,1 in-bounds
                af[cur][mt] = a;
            }
        }
    }

    // ---- epilogue (verified): D[m = quad*4 + r][n = l16]
#pragma unroll
    for (int mt = 0; mt < 5; ++mt) {
        const int d = wm * 80 + mt * 16 + quad * 4;
#pragma unroll
        for (int nt = 0; nt < 2; ++nt) {
            float* ob = out + ((size_t)b * DD1 + d) * TT + T0 + wn * 32 + nt * 16 + l16;
#pragma unroll
            for (int r = 0; r < 4; ++r)
                ob[(size_t)r * TT] = acc[mt][nt][r];
        }
    }
}

extern "C" void kernel_launch(void* const* d_in, const int* in_sizes, int n_in,
                              void* d_out, int out_size, void* d_ws, size_t ws_size,
                              hipStream_t stream) {
    const float* X    = (const float*)d_in[0];   // [B, C, T]
    const int*   sidx = (const int*)  d_in[1];   // [B]
    const float* W    = (const float*)d_in[2];   // [S, D1, C]
    float*       out  = (float*)d_out;           // [B, D1, T]

    dim3 grid(BB, TT / NT);      // 128 x 8 = 1024 blocks (MT=320: all d per block)
    dim3 block(512);

    const size_t need = (size_t)8 * DD1 * CC * sizeof(__bf16);   // 1,392,640 B
    if (d_ws && ws_size >= need) {
        __bf16* Wb = (__bf16*)d_ws;
        w_cvt<<<dim3(340), dim3(256), 0, stream>>>(W, Wb);
        subj_conv_deep<true><<<grid, block, 0, stream>>>(X, sidx, W, Wb, out);
    } else {
        subj_conv_deep<false><<<grid, block, 0, stream>>>(X, sidx, W, nullptr, out);
    }
}